// Round 1
// baseline (408.531 us; speedup 1.0000x reference)
//
#include <hip/hip_runtime.h>
#include <hip/hip_bf16.h>

typedef unsigned short ushort_t;
typedef unsigned int uint_t;

#define KL 1024
#define IL 8192
#define DIMV 128
#define NS 16
#define NB 258               // 32-col blocks per strip (258*32 = 8256 skewed steps)
#define NIT 269              // covers wave3 (i<=266) + export (267) + publish (268)
#define SSH (8256*64)        // ushorts per strip of c_h (fp16, pair-packed)
#define GATE 416             // cross-wg start cushion: 13 blocks * 32 cols
#define INF __builtin_inff()

typedef __attribute__((ext_vector_type(8))) short v8s;   // bf16x8 MFMA A/B frag
typedef __attribute__((ext_vector_type(4))) float v4f;   // MFMA C/D frag

// ---------------- kernel 1: squared row norms + zero flags ----------------
__global__ __launch_bounds__(256) void knorms(
    const float* __restrict__ kern, const float* __restrict__ xx,
    float* __restrict__ x2, float* __restrict__ k2, int* __restrict__ flags) {
  if (blockIdx.x == 0 && threadIdx.x < NS) flags[threadIdx.x] = 0;
  const int lane = threadIdx.x & 63;
  const int row = blockIdx.x * 4 + (threadIdx.x >> 6);
  const float* src;
  float* dst;
  if (row < IL) { src = xx + (size_t)row * DIMV; dst = x2 + row; }
  else          { src = kern + (size_t)(row - IL) * DIMV; dst = k2 + (row - IL); }
  float2 v = *(const float2*)(src + lane * 2);
  float ss = v.x * v.x + v.y * v.y;
  #pragma unroll
  for (int off = 32; off > 0; off >>= 1) ss += __shfl_down(ss, off, 64);
  if (lane == 0) *dst = ss;
}

// ---------------- kernel 2: MFMA bf16 GEMM -> c (fp16), diagonal-skew-stored ----
// c_h[s][tp][l] packs (c at t=2tp, t=2tp+1) for row 64s+l, t = col + l
__device__ __forceinline__ v8s pack_bf16x8(float4 a, float4 b) {
  union { unsigned int u[4]; v8s v; } r;
  union { __hip_bfloat162 h; unsigned int u; } t;
  t.h = __float22bfloat162_rn(make_float2(a.x, a.y)); r.u[0] = t.u;
  t.h = __float22bfloat162_rn(make_float2(a.z, a.w)); r.u[1] = t.u;
  t.h = __float22bfloat162_rn(make_float2(b.x, b.y)); r.u[2] = t.u;
  t.h = __float22bfloat162_rn(make_float2(b.z, b.w)); r.u[3] = t.u;
  return r.v;
}

__global__ __launch_bounds__(256) void kgemm(
    const float* __restrict__ kern, const float* __restrict__ xx,
    const float* __restrict__ x2, const float* __restrict__ k2,
    ushort_t* __restrict__ c_h) {
  __shared__ float ctile[64 * 64];   // [n=x-col][m-swizzled]
  const int T = threadIdx.x;
  const int w = T >> 6;
  const int lane = T & 63;
  const int lo = lane & 15;
  const int hi = lane >> 4;
  const int i0 = blockIdx.x * 64;    // DTW columns (x rows)
  const int s  = blockIdx.y;         // strip
  const int kr0 = s * 64;

  v4f acc[4] = {};
  #pragma unroll
  for (int ks = 0; ks < 4; ks++) {
    const int k = ks * 32 + hi * 8;
    const float* bp = xx + (size_t)(i0 + w * 16 + lo) * DIMV + k;
    v8s bf = pack_bf16x8(*(const float4*)bp, *(const float4*)(bp + 4));
    #pragma unroll
    for (int rt = 0; rt < 4; rt++) {
      const float* ap = kern + (size_t)(kr0 + rt * 16 + lo) * DIMV + k;
      v8s af = pack_bf16x8(*(const float4*)ap, *(const float4*)(ap + 4));
      acc[rt] = __builtin_amdgcn_mfma_f32_16x16x32_bf16(af, bf, acc[rt], 0, 0, 0);
    }
  }
  const float x2v = x2[i0 + w * 16 + lo];
  const int n_local = w * 16 + lo;
  #pragma unroll
  for (int rt = 0; rt < 4; rt++) {
    float4 k2f = *(const float4*)&k2[kr0 + rt * 16 + hi * 4];
    #pragma unroll
    for (int q = 0; q < 4; q++) {
      const int m_local = rt * 16 + hi * 4 + q;
      float cval = fmaxf((&k2f.x)[q] + x2v - 2.f * acc[rt][q], 0.f);
      ctile[n_local * 64 + ((m_local + 2 * n_local) & 63)] = cval;
    }
  }
  __syncthreads();
  // skew-scatter as fp16 pairs: element (t = i0+tt, lane=dk)
  _Float16* ob = (_Float16*)(c_h + (size_t)s * SSH);
  #pragma unroll
  for (int q = 0; q < 32; q++) {
    int tt = w + q * 4;              // local skewed row in [0,126]
    int di = tt - lane;
    if (tt <= 126 && di >= 0 && di < 64) {
      int t = i0 + tt;
      ob[((size_t)(t >> 1) * 64 + lane) * 2 + (t & 1)] =
          (_Float16)ctile[di * 64 + ((lane + 2 * di) & 63)];
    }
  }
}

// ---------------- kernel 3: 4 strips per workgroup, 6 waves, lag-3 pipeline ----------------
// This revision: 3-slot cbuf + stage-2-ahead streamer with counted s_waitcnt vmcnt(16)
// (never drain to 0 in-loop), and sync-wave drain deferred to start-of-next-iteration.
// Removes per-iteration L3/cross-XCD load latency from the barrier path.
__device__ __forceinline__ float dpp_wave_shr1(float oldv, float src) {
  return __int_as_float(__builtin_amdgcn_update_dpp(
      __float_as_int(oldv), __float_as_int(src), 0x138, 0xF, 0xF, false));
}
__device__ __forceinline__ float dpp_wave_rol1(float src) {
  return __int_as_float(__builtin_amdgcn_update_dpp(
      __float_as_int(src), __float_as_int(src), 0x134, 0xF, 0xF, false));
}
__device__ __forceinline__ float dpp_wave_shl1(float oldv, float src) {
  return __int_as_float(__builtin_amdgcn_update_dpp(
      __float_as_int(oldv), __float_as_int(src), 0x130, 0xF, 0xF, false));
}

__global__ __launch_bounds__(384) void kdp(
    const ushort_t* __restrict__ c_h, float* __restrict__ bound,
    int* __restrict__ flags, float* __restrict__ out) {
  __shared__ uint_t cbuf[4 * 3 * 1024];   // strip k, slot s: (k*3+s)*1024 uints (48 KB)
  __shared__ float ring[4 * 4 * 32];      // wave k out-ring: ring + k*128; slot q = cols 32q..32q+31
  __shared__ float feed[4 * 32];          // sync -> wave0 feed ring
  __shared__ uint_t dump[1024];           // landing pad for edge dummy loads (keeps count at 16)
  const int g = blockIdx.x;
  const int wv = threadIdx.x >> 6;        // 0..3 DP, 4 streamer, 5 sync
  const int lane = threadIdx.x & 63;
  const int sb = g * 4;

  float Dcur = INF, Dul = INF, Bout = INF;
  int fchk = 0, fpend = 0;
  float rfeed = INF;
  const float* bin = bound + (size_t)(sb > 0 ? sb - 1 : 0) * IL;
  float* bout3 = bound + (size_t)(sb + 3) * IL;

  // ---- pre-loop staging ----
  if (wv == 4) {
    // stage strip 0 blocks 0,1 -> slots 0,1 (in-loop staging starts at B=2)
    const char* gs = (const char*)(c_h + (size_t)sb * SSH);
    #pragma unroll
    for (int b = 0; b < 2; b++) {
      uint_t* dst = cbuf + b * 1024;
      #pragma unroll
      for (int q = 0; q < 4; q++)
        __builtin_amdgcn_global_load_lds(
            (const __attribute__((address_space(1))) void*)(gs + (size_t)b * 4096 + (size_t)q * 1024 + lane * 16),
            (__attribute__((address_space(3))) void*)(dst + q * 256 + lane * 4), 16, 0, 0);
    }
  } else if (wv == 5) {
    if (g > 0) {
      int f;
      do { f = __hip_atomic_load(&flags[sb - 1], __ATOMIC_RELAXED, __HIP_MEMORY_SCOPE_AGENT); } while (f < GATE);
      fchk = f; fpend = f;
      if (lane < 32) {
        feed[lane]      = __hip_atomic_load(&bin[lane],      __ATOMIC_RELAXED, __HIP_MEMORY_SCOPE_AGENT);
        feed[32 + lane] = __hip_atomic_load(&bin[32 + lane], __ATOMIC_RELAXED, __HIP_MEMORY_SCOPE_AGENT);
        rfeed           = __hip_atomic_load(&bin[64 + lane], __ATOMIC_RELAXED, __HIP_MEMORY_SCOPE_AGENT);
      }
    } else {
      if (lane < 32) { feed[lane] = INF; feed[32+lane] = INF; feed[64+lane] = INF; feed[96+lane] = INF; }
    }
  } else if (wv < 4) {
    if (g == 0 && wv == 0 && lane == 0) Dcur = 0.f;
  }
  __syncthreads();   // full drain once; streamer enters loop with vmcnt==0

  int s0 = 0;        // i % 3, maintained incrementally
  for (int i = 0; i < NIT; i++) {
    if (wv < 4) {
      // ---- DP wave k = wv, strip sb+k, block W = i - 3k (lag 3) ----
      const int W = i - 3 * wv;
      if (W >= 0 && W < NB) {
        // slot = W % 3 == i % 3 (lag is a multiple of 3)
        const uint_t* lc = cbuf + (wv * 3 + s0) * 1024 + lane;
        uint_t lv[16];
        #pragma unroll
        for (int tp = 0; tp < 16; tp++) lv[tp] = lc[tp * 64];
        float Bv = (wv == 0) ? feed[(W & 3) * 32 + (lane & 31)]
                             : ring[(wv - 1) * 128 + (W & 3) * 32 + (lane & 31)];
        float cvv[32];
        #pragma unroll
        for (int tp = 0; tp < 16; tp++) {
          union { uint_t u; _Float16 h[2]; } cu; cu.u = lv[tp];
          cvv[2 * tp]     = (float)cu.h[0];
          cvv[2 * tp + 1] = (float)cu.h[1];
        }
        if (W >= 2 && W < 256) {
          #pragma unroll
          for (int tt = 0; tt < 32; tt++) {
            float Dup = dpp_wave_shr1(Bv, Dcur);   // lane0 <- feed; lane m <- Dcur[m-1]
            float m1 = fminf(Dul, Dcur);           // parallel with dpp
            Bv = dpp_wave_rol1(Bv);
            Dcur = cvv[tt] + fminf(m1, Dup);
            Dul = Dup;
            Bout = dpp_wave_shl1(Dcur, Bout);      // lane63 injects bottom-row value
          }
        } else {
          const int t0 = W * 32;
          #pragma unroll
          for (int tt = 0; tt < 32; tt++) {
            const int t = t0 + tt;
            float Dup = dpp_wave_shr1(Bv, Dcur);
            float m1 = fminf(Dul, Dcur);
            Bv = dpp_wave_rol1(Bv);
            float Dnew = cvv[tt] + fminf(m1, Dup);
            const bool alo = (t >= lane);          // j >= 0
            const bool ahi = (t - lane < IL);      // j < IL
            if (alo) Dul = Dup;
            if (alo && ahi) Dcur = Dnew;
            Bout = dpp_wave_shl1(Dcur, Bout);
          }
        }
        // ring write (corrected): after block W, lane63 holds col 32(W-1) -> slot W-1 pos 0;
        // lanes 32..62 hold cols 32(W-2)+(l-31) -> slot W-2 pos l-31
        if (lane >= 32) {
          const int slot = (lane == 63) ? (W - 1) : (W - 2);
          if (slot >= 0)
            ring[wv * 128 + ((slot & 3) << 5) + ((lane + 1) & 31)] = Bout;
        }
      }
      __syncthreads();                        // DP waves: no VMEM ops, drain is free
    } else if (wv == 4) {
      // ---- streamer: stage strip k's block B = i+2-3k into slot (i+2)%3 ----
      int ip2 = s0 + 2; if (ip2 >= 3) ip2 -= 3;
      #pragma unroll
      for (int k = 0; k < 4; k++) {
        const int B = i + 2 - 3 * k;
        const bool ok = (B >= 0 && B < NB);
        const char* src = ok
            ? ((const char*)(c_h + (size_t)(sb + k) * SSH) + (size_t)B * 4096)
            : (const char*)c_h;               // dummy: valid memory, keeps issue count at 16
        uint_t* dst = ok ? (cbuf + (k * 3 + ip2) * 1024) : dump;
        #pragma unroll
        for (int q = 0; q < 4; q++)
          __builtin_amdgcn_global_load_lds(
              (const __attribute__((address_space(1))) void*)(src + (size_t)q * 1024 + lane * 16),
              (__attribute__((address_space(3))) void*)(dst + q * 256 + lane * 4), 16, 0, 0);
      }
      // counted wait: only loads issued LAST iteration (block i+1) must be complete
      // before this barrier; this iteration's 16 stay in flight across it.
      asm volatile("s_waitcnt vmcnt(16)" ::: "memory");
      __builtin_amdgcn_s_barrier();
    } else {
      // ---- sync wave ----
      // Drain PREVIOUS iteration's loads/stores here (they are ~1 T_iter old -> free).
      // This also orders iter i-1's export stores before this iter's flag publish.
      asm volatile("s_waitcnt vmcnt(0)" ::: "memory");
      if (g > 0) {
        if (fpend > fchk) fchk = fpend;           // consume last iter's flag load (drained)
        const int Fw = i + 2;                     // ds_write feed loaded last iter
        if (Fw >= 2 && Fw <= 255 && lane < 32) feed[(Fw & 3) * 32 + lane] = rfeed;
        const int Fl = i + 3;                     // issue next feed load
        if (Fl <= 255) {
          const int need = 32 * (Fl + 1);
          if (fchk < need) {                      // rare (cushion + tracking cover steady state)
            int f;
            do { f = __hip_atomic_load(&flags[sb - 1], __ATOMIC_RELAXED, __HIP_MEMORY_SCOPE_AGENT); } while (f < need);
            fchk = f;
          }
          if (lane < 32)
            rfeed = __hip_atomic_load(&bin[32 * Fl + lane], __ATOMIC_RELAXED, __HIP_MEMORY_SCOPE_AGENT);
        }
        fpend = __hip_atomic_load(&flags[sb - 1], __ATOMIC_RELAXED, __HIP_MEMORY_SCOPE_AGENT);
      }
      if (g < 3) {
        const int E = i - 12;                     // export wave3's boundary block E (slot done at E+11)
        if (E >= 0 && E < 256 && lane < 32) {
          float bv2 = ring[3 * 128 + (E & 3) * 32 + lane];
          __hip_atomic_store(&bout3[32 * E + lane], bv2, __ATOMIC_RELAXED, __HIP_MEMORY_SCOPE_AGENT);
        }
        const int Ep = i - 13;                    // publish E-1's export (drained at this iter's start)
        if (Ep >= 0 && Ep < 256 && lane == 0)
          __hip_atomic_store(&flags[sb + 3], 32 * Ep + 32, __ATOMIC_RELAXED, __HIP_MEMORY_SCOPE_AGENT);
      }
      asm volatile("s_waitcnt lgkmcnt(0)" ::: "memory");  // publish feed ds_write
      __builtin_amdgcn_s_barrier();
    }
    s0 = (s0 == 2) ? 0 : s0 + 1;
  }
  asm volatile("s_waitcnt vmcnt(0)" ::: "memory");  // quiesce in-flight DMA before endpgm
  if (g == 3 && wv == 3 && lane == 63) out[0] = Dcur;  // D[K-1][I-1] == optimal path sum
}

extern "C" void kernel_launch(void* const* d_in, const int* in_sizes, int n_in,
                              void* d_out, int out_size, void* d_ws, size_t ws_size,
                              hipStream_t stream) {
  const float* kern = (const float*)d_in[0]; // (1024,128)
  const float* xx   = (const float*)d_in[1]; // (8192,128)
  char* ws = (char*)d_ws;
  const size_t OFF_X2 = (size_t)NS * SSH * 2;           // c_h: ~16.9 MB
  const size_t OFF_K2 = OFF_X2 + (size_t)IL * 4;
  const size_t OFF_BD = OFF_K2 + (size_t)KL * 4;
  const size_t OFF_FL = OFF_BD + (size_t)NS * IL * 4;
  ushort_t* c_h  = (ushort_t*)ws;
  float* x2    = (float*)(ws + OFF_X2);
  float* k2    = (float*)(ws + OFF_K2);
  float* bnd   = (float*)(ws + OFF_BD);
  int*   flags = (int*)(ws + OFF_FL);

  knorms<<<(IL + KL) / 4, 256, 0, stream>>>(kern, xx, x2, k2, flags);
  kgemm<<<dim3(IL / 64, NS), 256, 0, stream>>>(kern, xx, x2, k2, c_h);
  kdp<<<4, 384, 0, stream>>>(c_h, bnd, flags, (float*)d_out);
}